// Round 16
// baseline (370.634 us; speedup 1.0000x reference)
//
#include <hip/hip_runtime.h>

#define N_   16384
#define D_   256
#define E_   262144
#define ET_  278528   // E_ + N_ (self loops)
#define DI_  512
#define CH_  512      // scan chunks
#define CL_  32       // chunk length (CH_*CL_ == N_)
#define GS_  16       // chunk-operator group size
#define NG_  32       // number of groups (CH_/GS_)
#define L2E_ 1.44269504f

typedef __attribute__((ext_vector_type(8))) short short8;
typedef __attribute__((ext_vector_type(4))) float f32x4;
typedef unsigned short ushort_t;

static __device__ __forceinline__ float wave_sum(float v){
#pragma unroll
  for (int m = 1; m < 64; m <<= 1) v += __shfl_xor(v, m);
  return v;
}
static __device__ __forceinline__ float wave_max(float v){
#pragma unroll
  for (int m = 1; m < 64; m <<= 1) v = fmaxf(v, __shfl_xor(v, m));
  return v;
}
static __device__ __forceinline__ float silu_f(float x){ return x / (1.f + __expf(-x)); }
static __device__ __forceinline__ float softplus_f(float v){
  return fmaxf(v, 0.f) + __logf(1.f + __expf(-fabsf(v)));
}
static __device__ __forceinline__ float fexp2(float x){ return __builtin_amdgcn_exp2f(x); }  // raw v_exp_f32
static __device__ __forceinline__ ushort_t f2b(float f){   // fp32 -> bf16 RNE
  unsigned u = __float_as_uint(f);
  return (ushort_t)((u + 0x7fffu + ((u >> 16) & 1u)) >> 16);
}
static __device__ __forceinline__ float b2f(ushort_t u){
  return __uint_as_float(((unsigned)u) << 16);
}
// global(AS1) -> LDS(AS3) 16B async stage; LDS dest = wave-uniform base + lane*16
#define GLDS16(gp, lp) __builtin_amdgcn_global_load_lds( \
    (const __attribute__((address_space(1))) unsigned int*)(gp), \
    (__attribute__((address_space(3))) unsigned int*)(lp), 16, 0, 0)

// ---------------------------------------------------------------- diagnostic marker (fires only if ws too small)
__global__ __launch_bounds__(256) void marker_kernel(float* __restrict__ out){
  out[threadIdx.x] = 1e9f;
}

// ---------------------------------------------------------------- permute x (3,N,256) fp32 -> xcat (N,768) bf16
__global__ __launch_bounds__(256) void permute_kernel(const float* __restrict__ x, ushort_t* __restrict__ xcat){
  int idx = blockIdx.x * 256 + threadIdx.x;      // over 3*16384*64 float4
  if (idx >= 3 * N_ * 64) return;
  int d4  = idx & 63;
  int n   = (idx >> 6) & (N_ - 1);
  int hop = idx >> 20;
  float4 v = ((const float4*)x)[((size_t)hop << 20) + ((size_t)n << 6) + d4];
  ushort4 o; o.x = f2b(v.x); o.y = f2b(v.y); o.z = f2b(v.z); o.w = f2b(v.w);
  ((ushort4*)xcat)[(size_t)n * 192 + hop * 64 + d4] = o;
}

// ---------------------------------------------------------------- weight transpose+convert: W[K x N] fp32 -> BT[Npad x K] bf16
__global__ __launch_bounds__(256) void wconv_kernel(const float* __restrict__ W, int K, int N,
                                                    ushort_t* __restrict__ BT){
  __shared__ float t[32][33];
  const int k0 = blockIdx.x * 32, n0 = blockIdx.y * 32;
  const int tr = threadIdx.x & 31, tc = threadIdx.x >> 5;
#pragma unroll
  for (int r = tc; r < 32; r += 8) {
    int k = k0 + r, n = n0 + tr;
    t[r][tr] = (k < K && n < N) ? W[(size_t)k * N + n] : 0.f;
  }
  __syncthreads();
#pragma unroll
  for (int r = tc; r < 32; r += 8) {
    int n = n0 + r, k = k0 + tr;
    BT[(size_t)n * K + k] = f2b(t[tr][r]);
  }
}

// ---------------------------------------------------------------- bf16 MFMA GEMM, 128x64 tile (MFMA-density-oriented)
// 4 waves 2x2: wave = 64 rows x 32 cols = 4x2 frags, 8 MFMA per K-step.
__global__ __launch_bounds__(256) void mgemm128_kernel(
    const ushort_t* __restrict__ A, int lda,
    const ushort_t* __restrict__ BT, int ldbt, int N,
    void* __restrict__ C, int ldc, int c_off, int c_bf16,
    const float* __restrict__ bias, const int* __restrict__ row_map, int K)
{
  __shared__ __align__(16) ushort_t Al[128 * 32];
  __shared__ __align__(16) ushort_t Bl[64 * 32];
  const int tid = threadIdx.x;
  const int lane = tid & 63;
  const int wid = tid >> 6;
  const int wr = wid >> 1, wc = wid & 1;
  const int m0 = blockIdx.x * 128, n0 = blockIdx.y * 64;
  const int fr = lane & 15, fq = lane >> 4;
  f32x4 acc[4][2] = {};
  for (int k0 = 0; k0 < K; k0 += 32) {
    __syncthreads();   // prev-iter LDS reads done before overwrite
#pragma unroll
    for (int i = 0; i < 2; ++i) {
      int f = i * 256 + tid;                 // 0..511: row=f>>2, colgroup=(f&3)*8
      GLDS16(&A[(size_t)(m0 + (f >> 2)) * lda + k0 + ((f & 3) << 3)],
             &Al[(size_t)(i * 256 + wid * 64) * 8]);
    }
    GLDS16(&BT[(size_t)(n0 + (tid >> 2)) * ldbt + k0 + ((tid & 3) << 3)],
           &Bl[(size_t)(wid * 64) * 8]);
    __syncthreads();   // drains vmcnt before LDS reads
    short8 af[4], bfr[2];
#pragma unroll
    for (int m = 0; m < 4; ++m) af[m]  = *(const short8*)&Al[(wr * 64 + m * 16 + fr) * 32 + fq * 8];
#pragma unroll
    for (int n = 0; n < 2; ++n) bfr[n] = *(const short8*)&Bl[(wc * 32 + n * 16 + fr) * 32 + fq * 8];
#pragma unroll
    for (int n = 0; n < 2; ++n)
#pragma unroll
      for (int m = 0; m < 4; ++m)
        acc[m][n] = __builtin_amdgcn_mfma_f32_16x16x32_bf16(af[m], bfr[n], acc[m][n], 0, 0, 0);
  }
  // epilogue: C col=lane&15, row=(lane>>4)*4+j  [m89-verified]
#pragma unroll
  for (int m = 0; m < 4; ++m)
#pragma unroll
    for (int n = 0; n < 2; ++n) {
      int col = n0 + wc * 32 + n * 16 + fr;
      if (col >= N) continue;
      float bv = bias ? bias[col] : 0.f;
#pragma unroll
      for (int j = 0; j < 4; ++j) {
        int row = m0 + wr * 64 + m * 16 + fq * 4 + j;
        int orow = row_map ? row_map[row] : row;
        float v = acc[m][n][j] + bv;
        if (c_bf16) ((ushort_t*)C)[(size_t)orow * ldc + c_off + col] = f2b(v);
        else        ((float*)C)   [(size_t)orow * ldc + c_off + col] = v;
      }
    }
}

// ---------------------------------------------------------------- bf16 MFMA GEMM, 64x64 tile (for tiny-N x_proj)
__global__ __launch_bounds__(256) void mgemm_kernel(
    const ushort_t* __restrict__ A, int lda,
    const ushort_t* __restrict__ BT, int ldbt, int N,
    void* __restrict__ C, int ldc, int c_off, int c_bf16,
    const float* __restrict__ bias, const int* __restrict__ row_map, int K)
{
  __shared__ __align__(16) ushort_t Al[64 * 32];
  __shared__ __align__(16) ushort_t Bl[64 * 32];
  const int tid = threadIdx.x;
  const int lane = tid & 63;
  const int wid = tid >> 6;
  const int wr = wid >> 1, wc = wid & 1;
  const int m0 = blockIdx.x * 64, n0 = blockIdx.y * 64;
  const int fr = lane & 15, fq = lane >> 4;
  const int srow = tid >> 2, scg = (tid & 3) << 3;   // staging: 64 rows x 4 col-groups
  f32x4 acc[2][2] = {};
  for (int k0 = 0; k0 < K; k0 += 32) {
    __syncthreads();
    GLDS16(&A [(size_t)(m0 + srow) * lda  + k0 + scg], &Al[(size_t)wid * 512]);
    GLDS16(&BT[(size_t)(n0 + srow) * ldbt + k0 + scg], &Bl[(size_t)wid * 512]);
    __syncthreads();
    short8 af[2], bfr[2];
#pragma unroll
    for (int m = 0; m < 2; ++m) af[m]  = *(const short8*)&Al[(wr * 32 + m * 16 + fr) * 32 + fq * 8];
#pragma unroll
    for (int n = 0; n < 2; ++n) bfr[n] = *(const short8*)&Bl[(wc * 32 + n * 16 + fr) * 32 + fq * 8];
#pragma unroll
    for (int n = 0; n < 2; ++n)
#pragma unroll
      for (int m = 0; m < 2; ++m)
        acc[m][n] = __builtin_amdgcn_mfma_f32_16x16x32_bf16(af[m], bfr[n], acc[m][n], 0, 0, 0);
  }
#pragma unroll
  for (int m = 0; m < 2; ++m)
#pragma unroll
    for (int n = 0; n < 2; ++n) {
      int col = n0 + wc * 32 + n * 16 + fr;
      if (col >= N) continue;
      float bv = bias ? bias[col] : 0.f;
#pragma unroll
      for (int j = 0; j < 4; ++j) {
        int row = m0 + wr * 32 + m * 16 + fq * 4 + j;
        int orow = row_map ? row_map[row] : row;
        float v = acc[m][n][j] + bv;
        if (c_bf16) ((ushort_t*)C)[(size_t)orow * ldc + c_off + col] = f2b(v);
        else        ((float*)C)   [(size_t)orow * ldc + c_off + col] = v;
      }
    }
}

// ---------------------------------------------------------------- rowwise LN(256) + silu: fp32 in -> bf16 out
__global__ __launch_bounds__(256) void ln_silu_kernel(const float* __restrict__ x, ushort_t* __restrict__ o8,
                                                      const float* __restrict__ g, const float* __restrict__ b){
  __shared__ float red[4];
  const int row = blockIdx.x; const int t = threadIdx.x;
  float v = x[(size_t)row * 256 + t];
  float sv = wave_sum(v);
  if ((t & 63) == 0) red[t >> 6] = sv;
  __syncthreads();
  float mean = (red[0] + red[1] + red[2] + red[3]) * (1.f / 256.f);
  __syncthreads();
  float dv = v - mean;
  float sq = wave_sum(dv * dv);
  if ((t & 63) == 0) red[t >> 6] = sq;
  __syncthreads();
  float var = (red[0] + red[1] + red[2] + red[3]) * (1.f / 256.f);
  float o = dv * rsqrtf(var + 1e-5f) * g[t] + b[t];
  o8[(size_t)row * 256 + t] = f2b(silu_f(o));
}

// ---------------------------------------------------------------- per-node attention logits (h bf16)
__global__ __launch_bounds__(256) void att_scores_kernel(const ushort_t* __restrict__ h, const float* __restrict__ asr,
                                                         const float* __restrict__ adt, float* __restrict__ as_, float* __restrict__ ad_){
  int wid = threadIdx.x >> 6, lane = threadIdx.x & 63;
  int n = blockIdx.x * 4 + wid;
  float s1 = 0.f, s2 = 0.f;
  for (int f = lane; f < 256; f += 64) {
    float hv = b2f(h[(size_t)n * 256 + f]);
    s1 = fmaf(hv, asr[f], s1); s2 = fmaf(hv, adt[f], s2);
  }
  s1 = wave_sum(s1); s2 = wave_sum(s2);
  if (lane == 0) { as_[n] = s1; ad_[n] = s2; }
}

// ---------------------------------------------------------------- CSR build
__global__ __launch_bounds__(256) void count_kernel(const int* __restrict__ ei, int* __restrict__ cnt_in, int* __restrict__ deg_out){
  int i = blockIdx.x * 256 + threadIdx.x;
  if (i >= ET_) return;
  int dst = (i < E_) ? ei[E_ + i] : (i - E_);
  atomicAdd(&cnt_in[dst], 1);
  if (i < E_) atomicAdd(&deg_out[ei[i]], 1);
}

__global__ __launch_bounds__(1024) void scan_offsets_kernel(const int* __restrict__ cnt, int* __restrict__ off, int* __restrict__ cursor){
  __shared__ int part[1024];
  int t = threadIdx.x;
  int base = t * 16;
  int local[16]; int s = 0;
#pragma unroll
  for (int i = 0; i < 16; ++i) { local[i] = s; s += cnt[base + i]; }
  part[t] = s; __syncthreads();
  for (int d = 1; d < 1024; d <<= 1) {
    int val = part[t];
    int add = (t >= d) ? part[t - d] : 0;
    __syncthreads();
    part[t] = val + add;
    __syncthreads();
  }
  int prev = (t > 0) ? part[t - 1] : 0;
#pragma unroll
  for (int i = 0; i < 16; ++i) { int o = prev + local[i]; off[base + i] = o; cursor[base + i] = o; }
  if (t == 1023) off[N_] = part[1023];
}

__global__ __launch_bounds__(256) void scatter_kernel(const int* __restrict__ ei, int* __restrict__ cursor, int* __restrict__ csr){
  int i = blockIdx.x * 256 + threadIdx.x;
  if (i >= ET_) return;
  int dst = (i < E_) ? ei[E_ + i] : (i - E_);
  int pos = atomicAdd(&cursor[dst], 1);
  csr[pos] = i;
}

// ---------------------------------------------------------------- GAT softmax + aggregate, wave-per-dst (4 dst/block, no barriers)
__global__ __launch_bounds__(256) void gat_agg_kernel(const int* __restrict__ ei, const int* __restrict__ off, const int* __restrict__ csr,
                                                      const float* __restrict__ as_, const float* __restrict__ ad_,
                                                      const ushort_t* __restrict__ h, const float* __restrict__ gat_b, ushort_t* __restrict__ cat){
  const int wv = threadIdx.x >> 6;
  const int lane = threadIdx.x & 63;
  const int dst = blockIdx.x * 4 + wv;
  __shared__ int   ssrc[4][256];
  __shared__ float se[4][256];
  const int o0 = off[dst];
  const int deg = off[dst + 1] - o0;
  const float adv = ad_[dst];
  float4 gb4 = *(const float4*)&gat_b[lane * 4];
  float a0 = gb4.x, a1 = gb4.y, a2 = gb4.z, a3 = gb4.w;
  if (deg <= 256) {
    float m = -1e30f;
    for (int j = lane; j < deg; j += 64) {
      int eid = csr[o0 + j];
      int src = (eid < E_) ? ei[eid] : (eid - E_);
      float e = as_[src] + adv;
      e = (e >= 0.f) ? e : 0.2f * e;
      ssrc[wv][j] = src; se[wv][j] = e;
      m = fmaxf(m, e);
    }
    m = wave_max(m);
    float dsum = 0.f;
    for (int j = lane; j < deg; j += 64) {
      float x = __expf(se[wv][j] - m);
      se[wv][j] = x; dsum += x;
    }
    dsum = wave_sum(dsum);
    float inv = 1.f / dsum;
    for (int j = 0; j < deg; ++j) {
      float wgt = se[wv][j] * inv;
      int src = ssrc[wv][j];
      ushort4 hv = *(const ushort4*)&h[(size_t)src * 256 + lane * 4];
      a0 = fmaf(wgt, b2f(hv.x), a0);
      a1 = fmaf(wgt, b2f(hv.y), a1);
      a2 = fmaf(wgt, b2f(hv.z), a2);
      a3 = fmaf(wgt, b2f(hv.w), a3);
    }
  } else {
    float m = -1e30f;
    for (int j = lane; j < deg; j += 64) {
      int eid = csr[o0 + j];
      int src = (eid < E_) ? ei[eid] : (eid - E_);
      float e = as_[src] + adv; e = (e >= 0.f) ? e : 0.2f * e;
      m = fmaxf(m, e);
    }
    m = wave_max(m);
    float dsum = 0.f;
    for (int j = lane; j < deg; j += 64) {
      int eid = csr[o0 + j];
      int src = (eid < E_) ? ei[eid] : (eid - E_);
      float e = as_[src] + adv; e = (e >= 0.f) ? e : 0.2f * e;
      dsum += __expf(e - m);
    }
    dsum = wave_sum(dsum);
    float inv = 1.f / dsum;
    for (int j = 0; j < deg; ++j) {
      int eid = csr[o0 + j];
      int src = (eid < E_) ? ei[eid] : (eid - E_);
      float e = as_[src] + adv; e = (e >= 0.f) ? e : 0.2f * e;
      float wgt = __expf(e - m) * inv;
      ushort4 hv = *(const ushort4*)&h[(size_t)src * 256 + lane * 4];
      a0 = fmaf(wgt, b2f(hv.x), a0);
      a1 = fmaf(wgt, b2f(hv.y), a1);
      a2 = fmaf(wgt, b2f(hv.z), a2);
      a3 = fmaf(wgt, b2f(hv.w), a3);
    }
  }
  ushort4 o; o.x = f2b(a0); o.y = f2b(a1); o.z = f2b(a2); o.w = f2b(a3);
  *(ushort4*)&cat[(size_t)dst * 512 + lane * 4] = o;
}

// ---------------------------------------------------------------- sort key
__global__ __launch_bounds__(256) void key_kernel(const int* __restrict__ degO, const float* __restrict__ noise, unsigned long long* __restrict__ keys){
  int n = blockIdx.x * 256 + threadIdx.x;
  if (n >= N_) return;
  float k = __fadd_rn((float)degO[n], __fmul_rn(noise[n], 0.1f));
  unsigned u = __float_as_uint(k);
  u = (u & 0x80000000u) ? ~u : (u | 0x80000000u);
  keys[n] = ((unsigned long long)u << 32) | (unsigned)n;
}

// ---------------------------------------------------------------- O(N^2) rank sort, j-split
__global__ __launch_bounds__(256) void rank_part_kernel(const unsigned long long* __restrict__ keys, int* __restrict__ rank){
  __shared__ unsigned long long tile[512];
  const int i = blockIdx.x * 256 + threadIdx.x;
  const unsigned long long ki = keys[i];
  const int base = blockIdx.y * 512;
  for (int j = threadIdx.x; j < 512; j += 256) tile[j] = keys[base + j];
  __syncthreads();
  int r = 0;
#pragma unroll 16
  for (int j = 0; j < 512; ++j) r += (tile[j] < ki);
  atomicAdd(&rank[i], r);
}
__global__ __launch_bounds__(256) void rank_scatter_kernel(const int* __restrict__ rank, int* __restrict__ sidx){
  int i = blockIdx.x * 256 + threadIdx.x;
  sidx[rank[i]] = i;
}

// ---------------------------------------------------------------- u0_bf = xf_bf[sidx] (bf16 rows, 512B)
__global__ __launch_bounds__(64) void gather_kernel(const ushort_t* __restrict__ xf, const int* __restrict__ sidx, ushort_t* __restrict__ u0){
  int i = blockIdx.x, t = threadIdx.x;
  ((uint2*)u0)[(size_t)i * 64 + t] = ((const uint2*)xf)[(size_t)sidx[i] * 64 + t];
}

// ---------------------------------------------------------------- causal depthwise conv (k=4) + silu; xz bf16 stride 1024 -> xm bf16
__global__ __launch_bounds__(256) void conv_silu_kernel(const ushort_t* __restrict__ xz, const float* __restrict__ cw, ushort_t* __restrict__ xm){
  int idx = blockIdx.x * 256 + threadIdx.x;          // over N_*64 channel-octets
  if (idx >= N_ * 64) return;
  int n = idx >> 6, oc = (idx & 63) << 3;
  float4 cwv[8];
#pragma unroll
  for (int j = 0; j < 8; ++j) cwv[j] = *(const float4*)&cw[(oc + j) * 4];
  short8 tap[4];
#pragma unroll
  for (int k = 0; k < 4; ++k) {
    int nn = n - 3 + k;
    if (nn >= 0) tap[k] = *(const short8*)&xz[(size_t)nn * 1024 + oc];
    else { short8 z = {}; tap[k] = z; }
  }
  float acc[8] = {};
#pragma unroll
  for (int k = 0; k < 4; ++k) {
#pragma unroll
    for (int j = 0; j < 8; ++j) {
      float xv = b2f((ushort_t)tap[k][j]);
      float wv = (&cwv[j].x)[k];
      acc[j] = fmaf(xv, wv, acc[j]);
    }
  }
  short8 o;
#pragma unroll
  for (int j = 0; j < 8; ++j) o[j] = (short)f2b(silu_f(acc[j]));
  *(short8*)&xm[(size_t)n * 512 + oc] = o;
}

// ================================================================ chunk-parallel selective scan (bf16 chunk-state buffers)
__global__ __launch_bounds__(256) void scan_p1_kernel(const float* __restrict__ xdbl,
    const float* __restrict__ dt_w, const float* __restrict__ dt_b, const float* __restrict__ A_log,
    float* __restrict__ a_sum, ushort_t* __restrict__ b_final)
{
  const int t = threadIdx.x;
  const int d = blockIdx.x * 256 + t;
  const int c = blockIdx.y;
  float Ac2[16];
#pragma unroll
  for (int k = 0; k < 16; ++k) Ac2[k] = -fexp2(A_log[d * 16 + k] * L2E_) * L2E_;
  const float dwv = dt_w[d], dbv = dt_b[d];
  __shared__ float sx[CL_];
  __shared__ __align__(16) float sB[CL_][16];
  for (int idx = t; idx < CL_ * 17; idx += 256) {
    float v = xdbl[(size_t)c * (CL_ * 17) + idx];
    int row = idx / 17, col = idx - row * 17;
    if (col == 0) sx[row] = v; else sB[row][col - 1] = v;
  }
  __syncthreads();
  float h[16] = {};
  float dts = 0.f;
  for (int i = 0; i < CL_; ++i) {
    float dtv = softplus_f(fmaf(sx[i], dwv, dbv));
    dts += dtv;
    float4 b0 = *(const float4*)&sB[i][0];
    float4 b1 = *(const float4*)&sB[i][4];
    float4 b2 = *(const float4*)&sB[i][8];
    float4 b3 = *(const float4*)&sB[i][12];
    h[0]  = fmaf(fexp2(Ac2[0]  * dtv), h[0],  dtv * b0.x);
    h[1]  = fmaf(fexp2(Ac2[1]  * dtv), h[1],  dtv * b0.y);
    h[2]  = fmaf(fexp2(Ac2[2]  * dtv), h[2],  dtv * b0.z);
    h[3]  = fmaf(fexp2(Ac2[3]  * dtv), h[3],  dtv * b0.w);
    h[4]  = fmaf(fexp2(Ac2[4]  * dtv), h[4],  dtv * b1.x);
    h[5]  = fmaf(fexp2(Ac2[5]  * dtv), h[5],  dtv * b1.y);
    h[6]  = fmaf(fexp2(Ac2[6]  * dtv), h[6],  dtv * b1.z);
    h[7]  = fmaf(fexp2(Ac2[7]  * dtv), h[7],  dtv * b1.w);
    h[8]  = fmaf(fexp2(Ac2[8]  * dtv), h[8],  dtv * b2.x);
    h[9]  = fmaf(fexp2(Ac2[9]  * dtv), h[9],  dtv * b2.y);
    h[10] = fmaf(fexp2(Ac2[10] * dtv), h[10], dtv * b2.z);
    h[11] = fmaf(fexp2(Ac2[11] * dtv), h[11], dtv * b2.w);
    h[12] = fmaf(fexp2(Ac2[12] * dtv), h[12], dtv * b3.x);
    h[13] = fmaf(fexp2(Ac2[13] * dtv), h[13], dtv * b3.y);
    h[14] = fmaf(fexp2(Ac2[14] * dtv), h[14], dtv * b3.z);
    h[15] = fmaf(fexp2(Ac2[15] * dtv), h[15], dtv * b3.w);
  }
  a_sum[c * 512 + d] = dts;
#pragma unroll
  for (int k = 0; k < 16; ++k) b_final[((size_t)c * 16 + k) * 512 + d] = f2b(h[k]);
}

__global__ __launch_bounds__(256) void scan_mid1_kernel(const float* __restrict__ a_sum,
    const ushort_t* __restrict__ b_final, const float* __restrict__ A_log,
    float* __restrict__ ga, ushort_t* __restrict__ gb)
{
  const int tid = blockIdx.x * 256 + threadIdx.x;
  const int d = tid & 511;
  const int s = (tid >> 9) & 15;
  const int g = tid >> 13;
  const float Ac2 = -fexp2(A_log[d * 16 + s] * L2E_) * L2E_;
  const int c0 = g * GS_;
  float ag = 0.f, Bg = 0.f;
  float an = a_sum[c0 * 512 + d];
  float bn = b2f(b_final[((size_t)c0 * 16 + s) * 512 + d]);
#pragma unroll
  for (int k = 0; k < GS_; ++k) {
    float a = an, b = bn;
    if (k + 1 < GS_) {
      an = a_sum[(c0 + k + 1) * 512 + d];
      bn = b2f(b_final[((size_t)(c0 + k + 1) * 16 + s) * 512 + d]);
    }
    Bg = fmaf(fexp2(Ac2 * a), Bg, b);
    ag += a;
  }
  gb[((size_t)g * 16 + s) * 512 + d] = f2b(Bg);
  if (s == 0) ga[g * 512 + d] = ag;
}

__global__ __launch_bounds__(256) void scan_mid2_kernel(const float* __restrict__ ga,
    const ushort_t* __restrict__ gb, const float* __restrict__ A_log, ushort_t* __restrict__ ginit)
{
  const int tid = blockIdx.x * 256 + threadIdx.x;
  const int d = tid & 511;
  const int s = tid >> 9;
  const float Ac2 = -fexp2(A_log[d * 16 + s] * L2E_) * L2E_;
  float gar[NG_], gbr[NG_];
#pragma unroll
  for (int g = 0; g < NG_; ++g) {
    gar[g] = ga[g * 512 + d];
    gbr[g] = b2f(gb[((size_t)g * 16 + s) * 512 + d]);
  }
  float h = 0.f;
#pragma unroll
  for (int g = 0; g < NG_; ++g) {
    ginit[((size_t)g * 16 + s) * 512 + d] = f2b(h);
    h = fmaf(fexp2(Ac2 * gar[g]), h, gbr[g]);
  }
}

__global__ __launch_bounds__(256) void scan_mid3_kernel(const float* __restrict__ a_sum,
    const ushort_t* __restrict__ b_final, const float* __restrict__ A_log,
    const ushort_t* __restrict__ ginit, ushort_t* __restrict__ init)
{
  const int tid = blockIdx.x * 256 + threadIdx.x;
  const int d = tid & 511;
  const int s = (tid >> 9) & 15;
  const int g = tid >> 13;
  const float Ac2 = -fexp2(A_log[d * 16 + s] * L2E_) * L2E_;
  const int c0 = g * GS_;
  float h = b2f(ginit[((size_t)g * 16 + s) * 512 + d]);
  float an = a_sum[c0 * 512 + d];
  float bn = b2f(b_final[((size_t)c0 * 16 + s) * 512 + d]);
#pragma unroll
  for (int k = 0; k < GS_; ++k) {
    float a = an, b = bn;
    if (k + 1 < GS_) {
      an = a_sum[(c0 + k + 1) * 512 + d];
      bn = b2f(b_final[((size_t)(c0 + k + 1) * 16 + s) * 512 + d]);
    }
    init[((size_t)(c0 + k) * 16 + s) * 512 + d] = f2b(h);
    h = fmaf(fexp2(Ac2 * a), h, b);
  }
}

// p3 fused ymod: y_bf = f2b((scan_y + xm*D) * silu(z)); xm bf16, z bf16 (xz col 512+d)
__global__ __launch_bounds__(256) void scan_p3_kernel(const float* __restrict__ xdbl,
    const float* __restrict__ dt_w, const float* __restrict__ dt_b, const float* __restrict__ A_log,
    const ushort_t* __restrict__ init, const ushort_t* __restrict__ xm, const float* __restrict__ Dp,
    const ushort_t* __restrict__ xz, ushort_t* __restrict__ y_bf)
{
  const int t = threadIdx.x;
  const int d = blockIdx.x * 256 + t;
  const int c = blockIdx.y;
  float Ac2[16];
#pragma unroll
  for (int k = 0; k < 16; ++k) Ac2[k] = -fexp2(A_log[d * 16 + k] * L2E_) * L2E_;
  const float dwv = dt_w[d], dbv = dt_b[d], dpv = Dp[d];
  __shared__ float sx[CL_];
  __shared__ __align__(16) float sB[CL_][16];
  for (int idx = t; idx < CL_ * 17; idx += 256) {
    float v = xdbl[(size_t)c * (CL_ * 17) + idx];
    int row = idx / 17, col = idx - row * 17;
    if (col == 0) sx[row] = v; else sB[row][col - 1] = v;
  }
  __syncthreads();
  float h[16];
#pragma unroll
  for (int k = 0; k < 16; ++k) h[k] = b2f(init[((size_t)c * 16 + k) * 512 + d]);
  const int n0 = c * CL_;
  const ushort_t* xmp = xm   + (size_t)n0 * 512  + d;
  const ushort_t* zp  = xz   + (size_t)n0 * 1024 + 512 + d;
  ushort_t*       yp  = y_bf + (size_t)n0 * 512  + d;
  for (int i = 0; i < CL_; ++i) {
    float dtv = softplus_f(fmaf(sx[i], dwv, dbv));
    float4 b0 = *(const float4*)&sB[i][0];
    float4 b1 = *(const float4*)&sB[i][4];
    float4 b2 = *(const float4*)&sB[i][8];
    float4 b3 = *(const float4*)&sB[i][12];
    h[0]  = fmaf(fexp2(Ac2[0]  * dtv), h[0],  dtv * b0.x);
    h[1]  = fmaf(fexp2(Ac2[1]  * dtv), h[1],  dtv * b0.y);
    h[2]  = fmaf(fexp2(Ac2[2]  * dtv), h[2],  dtv * b0.z);
    h[3]  = fmaf(fexp2(Ac2[3]  * dtv), h[3],  dtv * b0.w);
    h[4]  = fmaf(fexp2(Ac2[4]  * dtv), h[4],  dtv * b1.x);
    h[5]  = fmaf(fexp2(Ac2[5]  * dtv), h[5],  dtv * b1.y);
    h[6]  = fmaf(fexp2(Ac2[6]  * dtv), h[6],  dtv * b1.z);
    h[7]  = fmaf(fexp2(Ac2[7]  * dtv), h[7],  dtv * b1.w);
    h[8]  = fmaf(fexp2(Ac2[8]  * dtv), h[8],  dtv * b2.x);
    h[9]  = fmaf(fexp2(Ac2[9]  * dtv), h[9],  dtv * b2.y);
    h[10] = fmaf(fexp2(Ac2[10] * dtv), h[10], dtv * b2.z);
    h[11] = fmaf(fexp2(Ac2[11] * dtv), h[11], dtv * b2.w);
    h[12] = fmaf(fexp2(Ac2[12] * dtv), h[12], dtv * b3.x);
    h[13] = fmaf(fexp2(Ac2[13] * dtv), h[13], dtv * b3.y);
    h[14] = fmaf(fexp2(Ac2[14] * dtv), h[14], dtv * b3.z);
    h[15] = fmaf(fexp2(Ac2[15] * dtv), h[15], dtv * b3.w);
    float y = h[0] * b0.x;
    y = fmaf(h[1],  b0.y, y); y = fmaf(h[2],  b0.z, y); y = fmaf(h[3],  b0.w, y);
    y = fmaf(h[4],  b1.x, y); y = fmaf(h[5],  b1.y, y); y = fmaf(h[6],  b1.z, y);
    y = fmaf(h[7],  b1.w, y); y = fmaf(h[8],  b2.x, y); y = fmaf(h[9],  b2.y, y);
    y = fmaf(h[10], b2.z, y); y = fmaf(h[11], b2.w, y); y = fmaf(h[12], b3.x, y);
    y = fmaf(h[13], b3.y, y); y = fmaf(h[14], b3.z, y); y = fmaf(h[15], b3.w, y);
    float yv = fmaf(b2f(*xmp), dpv, y);
    float z = b2f(*zp);
    *yp = f2b(yv * silu_f(z));
    xmp += 512; zp += 1024; yp += 512;
  }
}

// ================================================================ host
extern "C" void kernel_launch(void* const* d_in, const int* in_sizes, int n_in,
                              void* d_out, int out_size, void* d_ws, size_t ws_size,
                              hipStream_t stream)
{
  (void)in_sizes; (void)n_in; (void)out_size;
  const float* x         = (const float*)d_in[0];
  const int*   ei        = (const int*)d_in[1];
  const float* pnoise    = (const float*)d_in[2];
  const float* hop_w     = (const float*)d_in[3];
  const float* hop_b     = (const float*)d_in[4];
  const float* hop_ln_g  = (const float*)d_in[5];
  const float* hop_ln_b  = (const float*)d_in[6];
  const float* gat_w     = (const float*)d_in[7];
  const float* att_src   = (const float*)d_in[8];
  const float* att_dst   = (const float*)d_in[9];
  const float* gat_b     = (const float*)d_in[10];
  const float* in_proj_w = (const float*)d_in[11];
  const float* conv_w    = (const float*)d_in[12];
  const float* x_proj_w  = (const float*)d_in[13];
  const float* dt_w      = (const float*)d_in[14];
  const float* dt_b      = (const float*)d_in[15];
  const float* A_log     = (const float*)d_in[16];
  const float* D_param   = (const float*)d_in[17];
  const float* out_w     = (const float*)d_in[18];
  const float* out_b     = (const float*)d_in[19];
  const float* mlp_w1    = (const float*)d_in[20];
  const float* mlp_b1    = (const float*)d_in[21];
  const float* mlp_ln_g  = (const float*)d_in[22];
  const float* mlp_ln_b  = (const float*)d_in[23];
  const float* mlp_w2    = (const float*)d_in[24];
  const float* mlp_b2    = (const float*)d_in[25];
  float* out = (float*)d_out;

  char* w = (char*)d_ws;
  auto alloc = [&](size_t bytes) -> void* {
    void* p = (void*)w; w += (bytes + 255) & ~(size_t)255; return p;
  };
  ushort_t* xz_bf  = (ushort_t*)alloc((size_t)N_ * 1024 * 2);  // 32 MiB: in_proj out (bf16); xcat_bf aliases
  float*    mlp1f  = (float*)alloc((size_t)N_ * 256 * 4);      // 16 MiB: hop out -> b_final(8MB) -> m1 out
  ushort_t* xf_bf  = (ushort_t*)alloc((size_t)N_ * 256 * 2);   // 8 MiB  (init aliases)
  ushort_t* h_bf   = (ushort_t*)alloc((size_t)N_ * 256 * 2);   // 8 MiB
  ushort_t* u0_bf  = (ushort_t*)alloc((size_t)N_ * 256 * 2);   // 8 MiB
  ushort_t* xm_bf  = (ushort_t*)alloc((size_t)N_ * 512 * 2);   // 16 MiB
  ushort_t* y_bf   = (ushort_t*)alloc((size_t)N_ * 512 * 2);   // 16 MiB
  ushort_t* cat_bf = (ushort_t*)alloc((size_t)N_ * 512 * 2);   // 16 MiB
  ushort_t* m1_bf  = (ushort_t*)alloc((size_t)N_ * 256 * 2);   // 8 MiB
  float*    xdbl   = (float*)alloc((size_t)N_ * 17 * 4);
  float*    as_    = (float*)alloc((size_t)N_ * 4);
  float*    ad_    = (float*)alloc((size_t)N_ * 4);
  float*    a_sum  = (float*)alloc((size_t)CH_ * 512 * 4);     // 1 MiB
  int* cnt    = (int*)alloc((size_t)N_ * 4);    // cnt, degO, rank contiguous for one memset
  int* degO   = (int*)alloc((size_t)N_ * 4);
  int* rank   = (int*)alloc((size_t)N_ * 4);
  int* cursor = (int*)alloc((size_t)N_ * 4);
  int* off    = (int*)alloc((size_t)(N_ + 1) * 4);
  int* sidx   = (int*)alloc((size_t)N_ * 4);
  int* csr    = (int*)alloc((size_t)ET_ * 4);
  unsigned long long* keys = (unsigned long long*)alloc((size_t)N_ * 8);
  float*    ga    = (float*)alloc((size_t)NG_ * 512 * 4);
  ushort_t* gb    = (ushort_t*)alloc((size_t)NG_ * 16 * 512 * 2);
  ushort_t* ginit = (ushort_t*)alloc((size_t)NG_ * 16 * 512 * 2);
  // bf16 transposed weight panels [rows x K], rows multiple of 64/128
  ushort_t* bt_hop = (ushort_t*)alloc((size_t)256 * 768 * 2);
  ushort_t* bt_gat = (ushort_t*)alloc((size_t)256 * 256 * 2);
  ushort_t* bt_inp = (ushort_t*)alloc((size_t)1024 * 256 * 2);
  ushort_t* bt_xp  = (ushort_t*)alloc((size_t)128 * 512 * 2);
  ushort_t* bt_out = (ushort_t*)alloc((size_t)256 * 512 * 2);
  ushort_t* bt_m1  = (ushort_t*)alloc((size_t)256 * 512 * 2);
  ushort_t* bt_m2  = (ushort_t*)alloc((size_t)256 * 256 * 2);
  // aliases (time-disjoint):
  ushort_t* xcat_bf = xz_bf;                 // 24 MiB (<32), dead after hop GEMM; xz_bf written step 8
  ushort_t* b_final = (ushort_t*)mlp1f;      // 8 MiB (<16), scan steps 11-13; mlp1f reborn step 15
  ushort_t* init    = xf_bf;                 // 8 MiB, xf_bf dead after step 8
  size_t needed = (size_t)(w - (char*)d_ws);
  if (needed > ws_size) {
    marker_kernel<<<1, 256, 0, stream>>>(out);
    return;
  }

  hipMemsetAsync(cnt, 0, 3 * (size_t)N_ * 4, stream);   // cnt + degO + rank

  // 0. weight panels (bf16, transposed)
  wconv_kernel<<<dim3(24, 8),  256, 0, stream>>>(hop_w,     768, 256,  bt_hop);
  wconv_kernel<<<dim3(8, 8),   256, 0, stream>>>(gat_w,     256, 256,  bt_gat);
  wconv_kernel<<<dim3(8, 32),  256, 0, stream>>>(in_proj_w, 256, 1024, bt_inp);
  wconv_kernel<<<dim3(16, 4),  256, 0, stream>>>(x_proj_w,  512, 17,   bt_xp);   // rows 17..127 zero
  wconv_kernel<<<dim3(16, 8),  256, 0, stream>>>(out_w,     512, 256,  bt_out);
  wconv_kernel<<<dim3(16, 8),  256, 0, stream>>>(mlp_w1,    512, 256,  bt_m1);
  wconv_kernel<<<dim3(8, 8),   256, 0, stream>>>(mlp_w2,    256, 256,  bt_m2);

  // 1. xcat_bf = permute(x) (bf16)
  permute_kernel<<<(3 * N_ * 64) / 256, 256, 0, stream>>>(x, xcat_bf);
  // 2. hop GEMM (fp32 out -> mlp1f) ; LN+silu -> xf_bf
  mgemm128_kernel<<<dim3(128, 4), 256, 0, stream>>>(xcat_bf, 768, bt_hop, 768, 256, mlp1f, 256, 0, 0, hop_b, nullptr, 768);
  ln_silu_kernel<<<N_, 256, 0, stream>>>(mlp1f, xf_bf, hop_ln_g, hop_ln_b);
  // 3. h_bf = xf_bf @ gat_w (bf16 out)
  mgemm128_kernel<<<dim3(128, 4), 256, 0, stream>>>(xf_bf, 256, bt_gat, 256, 256, h_bf, 256, 0, 1, nullptr, nullptr, 256);
  // 4. attention logits
  att_scores_kernel<<<N_ / 4, 256, 0, stream>>>(h_bf, att_src, att_dst, as_, ad_);
  // 5. CSR by dst + out-degree
  count_kernel<<<(ET_ + 255) / 256, 256, 0, stream>>>(ei, cnt, degO);
  scan_offsets_kernel<<<1, 1024, 0, stream>>>(cnt, off, cursor);
  scatter_kernel<<<(ET_ + 255) / 256, 256, 0, stream>>>(ei, cursor, csr);
  // 6. GAT -> cat_bf[:, :256] (wave-per-dst)
  gat_agg_kernel<<<N_ / 4, 256, 0, stream>>>(ei, off, csr, as_, ad_, h_bf, gat_b, cat_bf);
  // 7. stable argsort
  key_kernel<<<N_ / 256, 256, 0, stream>>>(degO, pnoise, keys);
  rank_part_kernel<<<dim3(N_ / 256, 32), 256, 0, stream>>>(keys, rank);
  rank_scatter_kernel<<<N_ / 256, 256, 0, stream>>>(rank, sidx);
  // 8. u0_bf = xf_bf[sidx]; xz_bf = u0_bf @ in_proj_w (bf16)
  gather_kernel<<<N_, 64, 0, stream>>>(xf_bf, sidx, u0_bf);
  mgemm128_kernel<<<dim3(128, 16), 256, 0, stream>>>(u0_bf, 256, bt_inp, 256, 1024, xz_bf, 1024, 0, 1, nullptr, nullptr, 256);
  // 9. conv + silu -> xm_bf
  conv_silu_kernel<<<(N_ * 64) / 256, 256, 0, stream>>>(xz_bf, conv_w, xm_bf);
  // 10. x_dbl = xm_bf @ x_proj_w (N=17, fp32, 64-tile for grid size)
  mgemm_kernel<<<dim3(256, 1), 256, 0, stream>>>(xm_bf, 512, bt_xp, 512, 17, xdbl, 17, 0, 0, nullptr, nullptr, 512);
  // 11-13. selective scan -> y_bf
  scan_p1_kernel<<<dim3(2, CH_), 256, 0, stream>>>(xdbl, dt_w, dt_b, A_log, a_sum, b_final);
  scan_mid1_kernel<<<(NG_ * 16 * 512) / 256, 256, 0, stream>>>(a_sum, b_final, A_log, ga, gb);
  scan_mid2_kernel<<<32, 256, 0, stream>>>(ga, gb, A_log, ginit);
  scan_mid3_kernel<<<(NG_ * 16 * 512) / 256, 256, 0, stream>>>(a_sum, b_final, A_log, ginit, init);
  scan_p3_kernel<<<dim3(2, CH_), 256, 0, stream>>>(xdbl, dt_w, dt_b, A_log, init, xm_bf, D_param, xz_bf, y_bf);
  // 14. x_mamba = y_bf @ out_w + out_b -> cat_bf[:, 256:] (bf16, row-scattered)
  mgemm128_kernel<<<dim3(128, 4), 256, 0, stream>>>(y_bf, 512, bt_out, 512, 256, cat_bf, 512, 256, 1, out_b, sidx, 512);
  // 15. MLP
  mgemm128_kernel<<<dim3(128, 4), 256, 0, stream>>>(cat_bf, 512, bt_m1, 512, 256, mlp1f, 256, 0, 0, mlp_b1, nullptr, 512);
  ln_silu_kernel<<<N_, 256, 0, stream>>>(mlp1f, m1_bf, mlp_ln_g, mlp_ln_b);
  mgemm128_kernel<<<dim3(128, 4), 256, 0, stream>>>(m1_bf, 256, bt_m2, 256, 256, out, 256, 0, 0, mlp_b2, nullptr, 256);
}

// Round 17
// 352.794 us; speedup vs baseline: 1.0506x; 1.0506x over previous
//
#include <hip/hip_runtime.h>

#define N_   16384
#define D_   256
#define E_   262144
#define ET_  278528   // E_ + N_ (self loops)
#define DI_  512
#define CH_  512      // scan chunks
#define CL_  32       // chunk length (CH_*CL_ == N_)
#define GS_  16       // chunk-operator group size
#define NG_  32       // number of groups (CH_/GS_)
#define L2E_ 1.44269504f

typedef __attribute__((ext_vector_type(8))) short short8;
typedef __attribute__((ext_vector_type(4))) float f32x4;
typedef unsigned short ushort_t;

static __device__ __forceinline__ float wave_sum(float v){
#pragma unroll
  for (int m = 1; m < 64; m <<= 1) v += __shfl_xor(v, m);
  return v;
}
static __device__ __forceinline__ float wave_max(float v){
#pragma unroll
  for (int m = 1; m < 64; m <<= 1) v = fmaxf(v, __shfl_xor(v, m));
  return v;
}
static __device__ __forceinline__ float silu_f(float x){ return x / (1.f + __expf(-x)); }
static __device__ __forceinline__ float softplus_f(float v){
  return fmaxf(v, 0.f) + __logf(1.f + __expf(-fabsf(v)));
}
static __device__ __forceinline__ float fexp2(float x){ return __builtin_amdgcn_exp2f(x); }  // raw v_exp_f32
static __device__ __forceinline__ ushort_t f2b(float f){   // fp32 -> bf16 RNE
  unsigned u = __float_as_uint(f);
  return (ushort_t)((u + 0x7fffu + ((u >> 16) & 1u)) >> 16);
}
static __device__ __forceinline__ float b2f(ushort_t u){
  return __uint_as_float(((unsigned)u) << 16);
}
// global(AS1) -> LDS(AS3) 16B async stage; LDS dest = wave-uniform base + lane*16
#define GLDS16(gp, lp) __builtin_amdgcn_global_load_lds( \
    (const __attribute__((address_space(1))) unsigned int*)(gp), \
    (__attribute__((address_space(3))) unsigned int*)(lp), 16, 0, 0)

// ---------------------------------------------------------------- diagnostic marker (fires only if ws too small)
__global__ __launch_bounds__(256) void marker_kernel(float* __restrict__ out){
  out[threadIdx.x] = 1e9f;
}

// ---------------------------------------------------------------- permute x (3,N,256) fp32 -> xcat (N,768) bf16
__global__ __launch_bounds__(256) void permute_kernel(const float* __restrict__ x, ushort_t* __restrict__ xcat){
  int idx = blockIdx.x * 256 + threadIdx.x;      // over 3*16384*64 float4
  if (idx >= 3 * N_ * 64) return;
  int d4  = idx & 63;
  int n   = (idx >> 6) & (N_ - 1);
  int hop = idx >> 20;
  float4 v = ((const float4*)x)[((size_t)hop << 20) + ((size_t)n << 6) + d4];
  ushort4 o; o.x = f2b(v.x); o.y = f2b(v.y); o.z = f2b(v.z); o.w = f2b(v.w);
  ((ushort4*)xcat)[(size_t)n * 192 + hop * 64 + d4] = o;
}

// ---------------------------------------------------------------- weight transpose+convert: W[K x N] fp32 -> BT[Npad x K] bf16
__global__ __launch_bounds__(256) void wconv_kernel(const float* __restrict__ W, int K, int N,
                                                    ushort_t* __restrict__ BT){
  __shared__ float t[32][33];
  const int k0 = blockIdx.x * 32, n0 = blockIdx.y * 32;
  const int tr = threadIdx.x & 31, tc = threadIdx.x >> 5;
#pragma unroll
  for (int r = tc; r < 32; r += 8) {
    int k = k0 + r, n = n0 + tr;
    t[r][tr] = (k < K && n < N) ? W[(size_t)k * N + n] : 0.f;
  }
  __syncthreads();
#pragma unroll
  for (int r = tc; r < 32; r += 8) {
    int n = n0 + r, k = k0 + tr;
    BT[(size_t)n * K + k] = f2b(t[tr][r]);
  }
}

// ---------------------------------------------------------------- bf16 MFMA GEMM, 64x64 tile (occupancy-oriented)
__global__ __launch_bounds__(256) void mgemm_kernel(
    const ushort_t* __restrict__ A, int lda,
    const ushort_t* __restrict__ BT, int ldbt, int N,
    void* __restrict__ C, int ldc, int c_off, int c_bf16,
    const float* __restrict__ bias, const int* __restrict__ row_map, int K)
{
  __shared__ __align__(16) ushort_t Al[64 * 32];
  __shared__ __align__(16) ushort_t Bl[64 * 32];
  const int tid = threadIdx.x;
  const int lane = tid & 63;
  const int wid = tid >> 6;
  const int wr = wid >> 1, wc = wid & 1;
  const int m0 = blockIdx.x * 64, n0 = blockIdx.y * 64;
  const int fr = lane & 15, fq = lane >> 4;
  const int srow = tid >> 2, scg = (tid & 3) << 3;   // staging: 64 rows x 4 col-groups
  f32x4 acc[2][2] = {};
  for (int k0 = 0; k0 < K; k0 += 32) {
    __syncthreads();   // prev-iter LDS reads done before overwrite
    GLDS16(&A [(size_t)(m0 + srow) * lda  + k0 + scg], &Al[(size_t)wid * 512]);
    GLDS16(&BT[(size_t)(n0 + srow) * ldbt + k0 + scg], &Bl[(size_t)wid * 512]);
    __syncthreads();   // drains vmcnt before LDS reads
    short8 af[2], bfr[2];
#pragma unroll
    for (int m = 0; m < 2; ++m) af[m]  = *(const short8*)&Al[(wr * 32 + m * 16 + fr) * 32 + fq * 8];
#pragma unroll
    for (int n = 0; n < 2; ++n) bfr[n] = *(const short8*)&Bl[(wc * 32 + n * 16 + fr) * 32 + fq * 8];
#pragma unroll
    for (int n = 0; n < 2; ++n)
#pragma unroll
      for (int m = 0; m < 2; ++m)
        acc[m][n] = __builtin_amdgcn_mfma_f32_16x16x32_bf16(af[m], bfr[n], acc[m][n], 0, 0, 0);
  }
  // epilogue: C col=lane&15, row=(lane>>4)*4+j  [m89-verified]
#pragma unroll
  for (int m = 0; m < 2; ++m)
#pragma unroll
    for (int n = 0; n < 2; ++n) {
      int col = n0 + wc * 32 + n * 16 + fr;
      if (col >= N) continue;
      float bv = bias ? bias[col] : 0.f;
#pragma unroll
      for (int j = 0; j < 4; ++j) {
        int row = m0 + wr * 32 + m * 16 + fq * 4 + j;
        int orow = row_map ? row_map[row] : row;
        float v = acc[m][n][j] + bv;
        if (c_bf16) ((ushort_t*)C)[(size_t)orow * ldc + c_off + col] = f2b(v);
        else        ((float*)C)   [(size_t)orow * ldc + c_off + col] = v;
      }
    }
}

// ---------------------------------------------------------------- rowwise LN(256) + silu: fp32 in -> bf16 out
__global__ __launch_bounds__(256) void ln_silu_kernel(const float* __restrict__ x, ushort_t* __restrict__ o8,
                                                      const float* __restrict__ g, const float* __restrict__ b){
  __shared__ float red[4];
  const int row = blockIdx.x; const int t = threadIdx.x;
  float v = x[(size_t)row * 256 + t];
  float sv = wave_sum(v);
  if ((t & 63) == 0) red[t >> 6] = sv;
  __syncthreads();
  float mean = (red[0] + red[1] + red[2] + red[3]) * (1.f / 256.f);
  __syncthreads();
  float dv = v - mean;
  float sq = wave_sum(dv * dv);
  if ((t & 63) == 0) red[t >> 6] = sq;
  __syncthreads();
  float var = (red[0] + red[1] + red[2] + red[3]) * (1.f / 256.f);
  float o = dv * rsqrtf(var + 1e-5f) * g[t] + b[t];
  o8[(size_t)row * 256 + t] = f2b(silu_f(o));
}

// ---------------------------------------------------------------- per-node attention logits (h bf16)
__global__ __launch_bounds__(256) void att_scores_kernel(const ushort_t* __restrict__ h, const float* __restrict__ asr,
                                                         const float* __restrict__ adt, float* __restrict__ as_, float* __restrict__ ad_){
  int wid = threadIdx.x >> 6, lane = threadIdx.x & 63;
  int n = blockIdx.x * 4 + wid;
  float s1 = 0.f, s2 = 0.f;
  for (int f = lane; f < 256; f += 64) {
    float hv = b2f(h[(size_t)n * 256 + f]);
    s1 = fmaf(hv, asr[f], s1); s2 = fmaf(hv, adt[f], s2);
  }
  s1 = wave_sum(s1); s2 = wave_sum(s2);
  if (lane == 0) { as_[n] = s1; ad_[n] = s2; }
}

// ---------------------------------------------------------------- CSR build
__global__ __launch_bounds__(256) void count_kernel(const int* __restrict__ ei, int* __restrict__ cnt_in, int* __restrict__ deg_out){
  int i = blockIdx.x * 256 + threadIdx.x;
  if (i >= ET_) return;
  int dst = (i < E_) ? ei[E_ + i] : (i - E_);
  atomicAdd(&cnt_in[dst], 1);
  if (i < E_) atomicAdd(&deg_out[ei[i]], 1);
}

__global__ __launch_bounds__(1024) void scan_offsets_kernel(const int* __restrict__ cnt, int* __restrict__ off, int* __restrict__ cursor){
  __shared__ int part[1024];
  int t = threadIdx.x;
  int base = t * 16;
  int local[16]; int s = 0;
#pragma unroll
  for (int i = 0; i < 16; ++i) { local[i] = s; s += cnt[base + i]; }
  part[t] = s; __syncthreads();
  for (int d = 1; d < 1024; d <<= 1) {
    int val = part[t];
    int add = (t >= d) ? part[t - d] : 0;
    __syncthreads();
    part[t] = val + add;
    __syncthreads();
  }
  int prev = (t > 0) ? part[t - 1] : 0;
#pragma unroll
  for (int i = 0; i < 16; ++i) { int o = prev + local[i]; off[base + i] = o; cursor[base + i] = o; }
  if (t == 1023) off[N_] = part[1023];
}

__global__ __launch_bounds__(256) void scatter_kernel(const int* __restrict__ ei, int* __restrict__ cursor, int* __restrict__ csr){
  int i = blockIdx.x * 256 + threadIdx.x;
  if (i >= ET_) return;
  int dst = (i < E_) ? ei[E_ + i] : (i - E_);
  int pos = atomicAdd(&cursor[dst], 1);
  csr[pos] = i;
}

// ---------------------------------------------------------------- GAT softmax + aggregate, wave-per-dst (4 dst/block, no barriers)
__global__ __launch_bounds__(256) void gat_agg_kernel(const int* __restrict__ ei, const int* __restrict__ off, const int* __restrict__ csr,
                                                      const float* __restrict__ as_, const float* __restrict__ ad_,
                                                      const ushort_t* __restrict__ h, const float* __restrict__ gat_b, ushort_t* __restrict__ cat){
  const int wv = threadIdx.x >> 6;
  const int lane = threadIdx.x & 63;
  const int dst = blockIdx.x * 4 + wv;
  __shared__ int   ssrc[4][256];
  __shared__ float se[4][256];
  const int o0 = off[dst];
  const int deg = off[dst + 1] - o0;
  const float adv = ad_[dst];
  float4 gb4 = *(const float4*)&gat_b[lane * 4];
  float a0 = gb4.x, a1 = gb4.y, a2 = gb4.z, a3 = gb4.w;
  if (deg <= 256) {
    float m = -1e30f;
    for (int j = lane; j < deg; j += 64) {
      int eid = csr[o0 + j];
      int src = (eid < E_) ? ei[eid] : (eid - E_);
      float e = as_[src] + adv;
      e = (e >= 0.f) ? e : 0.2f * e;
      ssrc[wv][j] = src; se[wv][j] = e;
      m = fmaxf(m, e);
    }
    m = wave_max(m);
    float dsum = 0.f;
    for (int j = lane; j < deg; j += 64) {
      float x = __expf(se[wv][j] - m);
      se[wv][j] = x; dsum += x;
    }
    dsum = wave_sum(dsum);
    float inv = 1.f / dsum;
    for (int j = 0; j < deg; ++j) {
      float wgt = se[wv][j] * inv;
      int src = ssrc[wv][j];
      ushort4 hv = *(const ushort4*)&h[(size_t)src * 256 + lane * 4];
      a0 = fmaf(wgt, b2f(hv.x), a0);
      a1 = fmaf(wgt, b2f(hv.y), a1);
      a2 = fmaf(wgt, b2f(hv.z), a2);
      a3 = fmaf(wgt, b2f(hv.w), a3);
    }
  } else {
    float m = -1e30f;
    for (int j = lane; j < deg; j += 64) {
      int eid = csr[o0 + j];
      int src = (eid < E_) ? ei[eid] : (eid - E_);
      float e = as_[src] + adv; e = (e >= 0.f) ? e : 0.2f * e;
      m = fmaxf(m, e);
    }
    m = wave_max(m);
    float dsum = 0.f;
    for (int j = lane; j < deg; j += 64) {
      int eid = csr[o0 + j];
      int src = (eid < E_) ? ei[eid] : (eid - E_);
      float e = as_[src] + adv; e = (e >= 0.f) ? e : 0.2f * e;
      dsum += __expf(e - m);
    }
    dsum = wave_sum(dsum);
    float inv = 1.f / dsum;
    for (int j = 0; j < deg; ++j) {
      int eid = csr[o0 + j];
      int src = (eid < E_) ? ei[eid] : (eid - E_);
      float e = as_[src] + adv; e = (e >= 0.f) ? e : 0.2f * e;
      float wgt = __expf(e - m) * inv;
      ushort4 hv = *(const ushort4*)&h[(size_t)src * 256 + lane * 4];
      a0 = fmaf(wgt, b2f(hv.x), a0);
      a1 = fmaf(wgt, b2f(hv.y), a1);
      a2 = fmaf(wgt, b2f(hv.z), a2);
      a3 = fmaf(wgt, b2f(hv.w), a3);
    }
  }
  ushort4 o; o.x = f2b(a0); o.y = f2b(a1); o.z = f2b(a2); o.w = f2b(a3);
  *(ushort4*)&cat[(size_t)dst * 512 + lane * 4] = o;
}

// ---------------------------------------------------------------- sort key
__global__ __launch_bounds__(256) void key_kernel(const int* __restrict__ degO, const float* __restrict__ noise, unsigned long long* __restrict__ keys){
  int n = blockIdx.x * 256 + threadIdx.x;
  if (n >= N_) return;
  float k = __fadd_rn((float)degO[n], __fmul_rn(noise[n], 0.1f));
  unsigned u = __float_as_uint(k);
  u = (u & 0x80000000u) ? ~u : (u | 0x80000000u);
  keys[n] = ((unsigned long long)u << 32) | (unsigned)n;
}

// ---------------------------------------------------------------- O(N^2) rank sort, j-split
__global__ __launch_bounds__(256) void rank_part_kernel(const unsigned long long* __restrict__ keys, int* __restrict__ rank){
  __shared__ unsigned long long tile[512];
  const int i = blockIdx.x * 256 + threadIdx.x;
  const unsigned long long ki = keys[i];
  const int base = blockIdx.y * 512;
  for (int j = threadIdx.x; j < 512; j += 256) tile[j] = keys[base + j];
  __syncthreads();
  int r = 0;
#pragma unroll 16
  for (int j = 0; j < 512; ++j) r += (tile[j] < ki);
  atomicAdd(&rank[i], r);
}
__global__ __launch_bounds__(256) void rank_scatter_kernel(const int* __restrict__ rank, int* __restrict__ sidx){
  int i = blockIdx.x * 256 + threadIdx.x;
  sidx[rank[i]] = i;
}

// ---------------------------------------------------------------- u0_bf = xf_bf[sidx] (bf16 rows, 512B)
__global__ __launch_bounds__(64) void gather_kernel(const ushort_t* __restrict__ xf, const int* __restrict__ sidx, ushort_t* __restrict__ u0){
  int i = blockIdx.x, t = threadIdx.x;
  ((uint2*)u0)[(size_t)i * 64 + t] = ((const uint2*)xf)[(size_t)sidx[i] * 64 + t];
}

// ---------------------------------------------------------------- causal depthwise conv (k=4) + silu; xz bf16 stride 1024 -> xm bf16
__global__ __launch_bounds__(256) void conv_silu_kernel(const ushort_t* __restrict__ xz, const float* __restrict__ cw, ushort_t* __restrict__ xm){
  int idx = blockIdx.x * 256 + threadIdx.x;          // over N_*64 channel-octets
  if (idx >= N_ * 64) return;
  int n = idx >> 6, oc = (idx & 63) << 3;
  float4 cwv[8];
#pragma unroll
  for (int j = 0; j < 8; ++j) cwv[j] = *(const float4*)&cw[(oc + j) * 4];
  short8 tap[4];
#pragma unroll
  for (int k = 0; k < 4; ++k) {
    int nn = n - 3 + k;
    if (nn >= 0) tap[k] = *(const short8*)&xz[(size_t)nn * 1024 + oc];
    else { short8 z = {}; tap[k] = z; }
  }
  float acc[8] = {};
#pragma unroll
  for (int k = 0; k < 4; ++k) {
#pragma unroll
    for (int j = 0; j < 8; ++j) {
      float xv = b2f((ushort_t)tap[k][j]);
      float wv = (&cwv[j].x)[k];
      acc[j] = fmaf(xv, wv, acc[j]);
    }
  }
  short8 o;
#pragma unroll
  for (int j = 0; j < 8; ++j) o[j] = (short)f2b(silu_f(acc[j]));
  *(short8*)&xm[(size_t)n * 512 + oc] = o;
}

// ================================================================ chunk-parallel selective scan (bf16 chunk-state buffers)
__global__ __launch_bounds__(256) void scan_p1_kernel(const float* __restrict__ xdbl,
    const float* __restrict__ dt_w, const float* __restrict__ dt_b, const float* __restrict__ A_log,
    float* __restrict__ a_sum, ushort_t* __restrict__ b_final)
{
  const int t = threadIdx.x;
  const int d = blockIdx.x * 256 + t;
  const int c = blockIdx.y;
  float Ac2[16];
#pragma unroll
  for (int k = 0; k < 16; ++k) Ac2[k] = -fexp2(A_log[d * 16 + k] * L2E_) * L2E_;
  const float dwv = dt_w[d], dbv = dt_b[d];
  __shared__ float sx[CL_];
  __shared__ __align__(16) float sB[CL_][16];
  for (int idx = t; idx < CL_ * 17; idx += 256) {
    float v = xdbl[(size_t)c * (CL_ * 17) + idx];
    int row = idx / 17, col = idx - row * 17;
    if (col == 0) sx[row] = v; else sB[row][col - 1] = v;
  }
  __syncthreads();
  float h[16] = {};
  float dts = 0.f;
#pragma unroll 4
  for (int i = 0; i < CL_; ++i) {
    float dtv = softplus_f(fmaf(sx[i], dwv, dbv));
    dts += dtv;
    float4 b0 = *(const float4*)&sB[i][0];
    float4 b1 = *(const float4*)&sB[i][4];
    float4 b2 = *(const float4*)&sB[i][8];
    float4 b3 = *(const float4*)&sB[i][12];
    h[0]  = fmaf(fexp2(Ac2[0]  * dtv), h[0],  dtv * b0.x);
    h[1]  = fmaf(fexp2(Ac2[1]  * dtv), h[1],  dtv * b0.y);
    h[2]  = fmaf(fexp2(Ac2[2]  * dtv), h[2],  dtv * b0.z);
    h[3]  = fmaf(fexp2(Ac2[3]  * dtv), h[3],  dtv * b0.w);
    h[4]  = fmaf(fexp2(Ac2[4]  * dtv), h[4],  dtv * b1.x);
    h[5]  = fmaf(fexp2(Ac2[5]  * dtv), h[5],  dtv * b1.y);
    h[6]  = fmaf(fexp2(Ac2[6]  * dtv), h[6],  dtv * b1.z);
    h[7]  = fmaf(fexp2(Ac2[7]  * dtv), h[7],  dtv * b1.w);
    h[8]  = fmaf(fexp2(Ac2[8]  * dtv), h[8],  dtv * b2.x);
    h[9]  = fmaf(fexp2(Ac2[9]  * dtv), h[9],  dtv * b2.y);
    h[10] = fmaf(fexp2(Ac2[10] * dtv), h[10], dtv * b2.z);
    h[11] = fmaf(fexp2(Ac2[11] * dtv), h[11], dtv * b2.w);
    h[12] = fmaf(fexp2(Ac2[12] * dtv), h[12], dtv * b3.x);
    h[13] = fmaf(fexp2(Ac2[13] * dtv), h[13], dtv * b3.y);
    h[14] = fmaf(fexp2(Ac2[14] * dtv), h[14], dtv * b3.z);
    h[15] = fmaf(fexp2(Ac2[15] * dtv), h[15], dtv * b3.w);
  }
  a_sum[c * 512 + d] = dts;
#pragma unroll
  for (int k = 0; k < 16; ++k) b_final[((size_t)c * 16 + k) * 512 + d] = f2b(h[k]);
}

__global__ __launch_bounds__(256) void scan_mid1_kernel(const float* __restrict__ a_sum,
    const ushort_t* __restrict__ b_final, const float* __restrict__ A_log,
    float* __restrict__ ga, ushort_t* __restrict__ gb)
{
  const int tid = blockIdx.x * 256 + threadIdx.x;
  const int d = tid & 511;
  const int s = (tid >> 9) & 15;
  const int g = tid >> 13;
  const float Ac2 = -fexp2(A_log[d * 16 + s] * L2E_) * L2E_;
  const int c0 = g * GS_;
  float ag = 0.f, Bg = 0.f;
  float an = a_sum[c0 * 512 + d];
  float bn = b2f(b_final[((size_t)c0 * 16 + s) * 512 + d]);
#pragma unroll
  for (int k = 0; k < GS_; ++k) {
    float a = an, b = bn;
    if (k + 1 < GS_) {
      an = a_sum[(c0 + k + 1) * 512 + d];
      bn = b2f(b_final[((size_t)(c0 + k + 1) * 16 + s) * 512 + d]);
    }
    Bg = fmaf(fexp2(Ac2 * a), Bg, b);
    ag += a;
  }
  gb[((size_t)g * 16 + s) * 512 + d] = f2b(Bg);
  if (s == 0) ga[g * 512 + d] = ag;
}

__global__ __launch_bounds__(256) void scan_mid2_kernel(const float* __restrict__ ga,
    const ushort_t* __restrict__ gb, const float* __restrict__ A_log, ushort_t* __restrict__ ginit)
{
  const int tid = blockIdx.x * 256 + threadIdx.x;
  const int d = tid & 511;
  const int s = tid >> 9;
  const float Ac2 = -fexp2(A_log[d * 16 + s] * L2E_) * L2E_;
  float gar[NG_], gbr[NG_];
#pragma unroll
  for (int g = 0; g < NG_; ++g) {
    gar[g] = ga[g * 512 + d];
    gbr[g] = b2f(gb[((size_t)g * 16 + s) * 512 + d]);
  }
  float h = 0.f;
#pragma unroll
  for (int g = 0; g < NG_; ++g) {
    ginit[((size_t)g * 16 + s) * 512 + d] = f2b(h);
    h = fmaf(fexp2(Ac2 * gar[g]), h, gbr[g]);
  }
}

__global__ __launch_bounds__(256) void scan_mid3_kernel(const float* __restrict__ a_sum,
    const ushort_t* __restrict__ b_final, const float* __restrict__ A_log,
    const ushort_t* __restrict__ ginit, ushort_t* __restrict__ init)
{
  const int tid = blockIdx.x * 256 + threadIdx.x;
  const int d = tid & 511;
  const int s = (tid >> 9) & 15;
  const int g = tid >> 13;
  const float Ac2 = -fexp2(A_log[d * 16 + s] * L2E_) * L2E_;
  const int c0 = g * GS_;
  float h = b2f(ginit[((size_t)g * 16 + s) * 512 + d]);
  float an = a_sum[c0 * 512 + d];
  float bn = b2f(b_final[((size_t)c0 * 16 + s) * 512 + d]);
#pragma unroll
  for (int k = 0; k < GS_; ++k) {
    float a = an, b = bn;
    if (k + 1 < GS_) {
      an = a_sum[(c0 + k + 1) * 512 + d];
      bn = b2f(b_final[((size_t)(c0 + k + 1) * 16 + s) * 512 + d]);
    }
    init[((size_t)(c0 + k) * 16 + s) * 512 + d] = f2b(h);
    h = fmaf(fexp2(Ac2 * a), h, b);
  }
}

// p3 fused ymod: y_bf = f2b((scan_y + xm*D) * silu(z)); xm bf16, z bf16 (xz col 512+d)
__global__ __launch_bounds__(256) void scan_p3_kernel(const float* __restrict__ xdbl,
    const float* __restrict__ dt_w, const float* __restrict__ dt_b, const float* __restrict__ A_log,
    const ushort_t* __restrict__ init, const ushort_t* __restrict__ xm, const float* __restrict__ Dp,
    const ushort_t* __restrict__ xz, ushort_t* __restrict__ y_bf)
{
  const int t = threadIdx.x;
  const int d = blockIdx.x * 256 + t;
  const int c = blockIdx.y;
  float Ac2[16];
#pragma unroll
  for (int k = 0; k < 16; ++k) Ac2[k] = -fexp2(A_log[d * 16 + k] * L2E_) * L2E_;
  const float dwv = dt_w[d], dbv = dt_b[d], dpv = Dp[d];
  __shared__ float sx[CL_];
  __shared__ __align__(16) float sB[CL_][16];
  for (int idx = t; idx < CL_ * 17; idx += 256) {
    float v = xdbl[(size_t)c * (CL_ * 17) + idx];
    int row = idx / 17, col = idx - row * 17;
    if (col == 0) sx[row] = v; else sB[row][col - 1] = v;
  }
  __syncthreads();
  float h[16];
#pragma unroll
  for (int k = 0; k < 16; ++k) h[k] = b2f(init[((size_t)c * 16 + k) * 512 + d]);
  const int n0 = c * CL_;
  const ushort_t* xmp = xm   + (size_t)n0 * 512  + d;
  const ushort_t* zp  = xz   + (size_t)n0 * 1024 + 512 + d;
  ushort_t*       yp  = y_bf + (size_t)n0 * 512  + d;
#pragma unroll 4
  for (int i = 0; i < CL_; ++i) {
    float dtv = softplus_f(fmaf(sx[i], dwv, dbv));
    float4 b0 = *(const float4*)&sB[i][0];
    float4 b1 = *(const float4*)&sB[i][4];
    float4 b2 = *(const float4*)&sB[i][8];
    float4 b3 = *(const float4*)&sB[i][12];
    h[0]  = fmaf(fexp2(Ac2[0]  * dtv), h[0],  dtv * b0.x);
    h[1]  = fmaf(fexp2(Ac2[1]  * dtv), h[1],  dtv * b0.y);
    h[2]  = fmaf(fexp2(Ac2[2]  * dtv), h[2],  dtv * b0.z);
    h[3]  = fmaf(fexp2(Ac2[3]  * dtv), h[3],  dtv * b0.w);
    h[4]  = fmaf(fexp2(Ac2[4]  * dtv), h[4],  dtv * b1.x);
    h[5]  = fmaf(fexp2(Ac2[5]  * dtv), h[5],  dtv * b1.y);
    h[6]  = fmaf(fexp2(Ac2[6]  * dtv), h[6],  dtv * b1.z);
    h[7]  = fmaf(fexp2(Ac2[7]  * dtv), h[7],  dtv * b1.w);
    h[8]  = fmaf(fexp2(Ac2[8]  * dtv), h[8],  dtv * b2.x);
    h[9]  = fmaf(fexp2(Ac2[9]  * dtv), h[9],  dtv * b2.y);
    h[10] = fmaf(fexp2(Ac2[10] * dtv), h[10], dtv * b2.z);
    h[11] = fmaf(fexp2(Ac2[11] * dtv), h[11], dtv * b2.w);
    h[12] = fmaf(fexp2(Ac2[12] * dtv), h[12], dtv * b3.x);
    h[13] = fmaf(fexp2(Ac2[13] * dtv), h[13], dtv * b3.y);
    h[14] = fmaf(fexp2(Ac2[14] * dtv), h[14], dtv * b3.z);
    h[15] = fmaf(fexp2(Ac2[15] * dtv), h[15], dtv * b3.w);
    float y = h[0] * b0.x;
    y = fmaf(h[1],  b0.y, y); y = fmaf(h[2],  b0.z, y); y = fmaf(h[3],  b0.w, y);
    y = fmaf(h[4],  b1.x, y); y = fmaf(h[5],  b1.y, y); y = fmaf(h[6],  b1.z, y);
    y = fmaf(h[7],  b1.w, y); y = fmaf(h[8],  b2.x, y); y = fmaf(h[9],  b2.y, y);
    y = fmaf(h[10], b2.z, y); y = fmaf(h[11], b2.w, y); y = fmaf(h[12], b3.x, y);
    y = fmaf(h[13], b3.y, y); y = fmaf(h[14], b3.z, y); y = fmaf(h[15], b3.w, y);
    float yv = fmaf(b2f(*xmp), dpv, y);
    float z = b2f(*zp);
    *yp = f2b(yv * silu_f(z));
    xmp += 512; zp += 1024; yp += 512;
  }
}

// ================================================================ host
extern "C" void kernel_launch(void* const* d_in, const int* in_sizes, int n_in,
                              void* d_out, int out_size, void* d_ws, size_t ws_size,
                              hipStream_t stream)
{
  (void)in_sizes; (void)n_in; (void)out_size;
  const float* x         = (const float*)d_in[0];
  const int*   ei        = (const int*)d_in[1];
  const float* pnoise    = (const float*)d_in[2];
  const float* hop_w     = (const float*)d_in[3];
  const float* hop_b     = (const float*)d_in[4];
  const float* hop_ln_g  = (const float*)d_in[5];
  const float* hop_ln_b  = (const float*)d_in[6];
  const float* gat_w     = (const float*)d_in[7];
  const float* att_src   = (const float*)d_in[8];
  const float* att_dst   = (const float*)d_in[9];
  const float* gat_b     = (const float*)d_in[10];
  const float* in_proj_w = (const float*)d_in[11];
  const float* conv_w    = (const float*)d_in[12];
  const float* x_proj_w  = (const float*)d_in[13];
  const float* dt_w      = (const float*)d_in[14];
  const float* dt_b      = (const float*)d_in[15];
  const float* A_log     = (const float*)d_in[16];
  const float* D_param   = (const float*)d_in[17];
  const float* out_w     = (const float*)d_in[18];
  const float* out_b     = (const float*)d_in[19];
  const float* mlp_w1    = (const float*)d_in[20];
  const float* mlp_b1    = (const float*)d_in[21];
  const float* mlp_ln_g  = (const float*)d_in[22];
  const float* mlp_ln_b  = (const float*)d_in[23];
  const float* mlp_w2    = (const float*)d_in[24];
  const float* mlp_b2    = (const float*)d_in[25];
  float* out = (float*)d_out;

  char* w = (char*)d_ws;
  auto alloc = [&](size_t bytes) -> void* {
    void* p = (void*)w; w += (bytes + 255) & ~(size_t)255; return p;
  };
  ushort_t* xz_bf  = (ushort_t*)alloc((size_t)N_ * 1024 * 2);  // 32 MiB: in_proj out (bf16); xcat_bf aliases
  float*    mlp1f  = (float*)alloc((size_t)N_ * 256 * 4);      // 16 MiB: hop out -> b_final(8MB) -> m1 out
  ushort_t* xf_bf  = (ushort_t*)alloc((size_t)N_ * 256 * 2);   // 8 MiB  (init aliases)
  ushort_t* h_bf   = (ushort_t*)alloc((size_t)N_ * 256 * 2);   // 8 MiB
  ushort_t* u0_bf  = (ushort_t*)alloc((size_t)N_ * 256 * 2);   // 8 MiB
  ushort_t* xm_bf  = (ushort_t*)alloc((size_t)N_ * 512 * 2);   // 16 MiB
  ushort_t* y_bf   = (ushort_t*)alloc((size_t)N_ * 512 * 2);   // 16 MiB
  ushort_t* cat_bf = (ushort_t*)alloc((size_t)N_ * 512 * 2);   // 16 MiB
  ushort_t* m1_bf  = (ushort_t*)alloc((size_t)N_ * 256 * 2);   // 8 MiB
  float*    xdbl   = (float*)alloc((size_t)N_ * 17 * 4);
  float*    as_    = (float*)alloc((size_t)N_ * 4);
  float*    ad_    = (float*)alloc((size_t)N_ * 4);
  float*    a_sum  = (float*)alloc((size_t)CH_ * 512 * 4);     // 1 MiB
  int* cnt    = (int*)alloc((size_t)N_ * 4);    // cnt, degO, rank contiguous for one memset
  int* degO   = (int*)alloc((size_t)N_ * 4);
  int* rank   = (int*)alloc((size_t)N_ * 4);
  int* cursor = (int*)alloc((size_t)N_ * 4);
  int* off    = (int*)alloc((size_t)(N_ + 1) * 4);
  int* sidx   = (int*)alloc((size_t)N_ * 4);
  int* csr    = (int*)alloc((size_t)ET_ * 4);
  unsigned long long* keys = (unsigned long long*)alloc((size_t)N_ * 8);
  float*    ga    = (float*)alloc((size_t)NG_ * 512 * 4);
  ushort_t* gb    = (ushort_t*)alloc((size_t)NG_ * 16 * 512 * 2);
  ushort_t* ginit = (ushort_t*)alloc((size_t)NG_ * 16 * 512 * 2);
  // bf16 transposed weight panels [rows x K], rows multiple of 64
  ushort_t* bt_hop = (ushort_t*)alloc((size_t)256 * 768 * 2);
  ushort_t* bt_gat = (ushort_t*)alloc((size_t)256 * 256 * 2);
  ushort_t* bt_inp = (ushort_t*)alloc((size_t)1024 * 256 * 2);
  ushort_t* bt_xp  = (ushort_t*)alloc((size_t)128 * 512 * 2);
  ushort_t* bt_out = (ushort_t*)alloc((size_t)256 * 512 * 2);
  ushort_t* bt_m1  = (ushort_t*)alloc((size_t)256 * 512 * 2);
  ushort_t* bt_m2  = (ushort_t*)alloc((size_t)256 * 256 * 2);
  // aliases (time-disjoint):
  ushort_t* xcat_bf = xz_bf;                 // 24 MiB (<32), dead after hop GEMM; xz_bf written step 8
  ushort_t* b_final = (ushort_t*)mlp1f;      // 8 MiB (<16), scan steps 11-13; mlp1f reborn step 15
  ushort_t* init    = xf_bf;                 // 8 MiB, xf_bf dead after step 8
  size_t needed = (size_t)(w - (char*)d_ws);
  if (needed > ws_size) {
    marker_kernel<<<1, 256, 0, stream>>>(out);
    return;
  }

  hipMemsetAsync(cnt, 0, 3 * (size_t)N_ * 4, stream);   // cnt + degO + rank

  // 0. weight panels (bf16, transposed)
  wconv_kernel<<<dim3(24, 8),  256, 0, stream>>>(hop_w,     768, 256,  bt_hop);
  wconv_kernel<<<dim3(8, 8),   256, 0, stream>>>(gat_w,     256, 256,  bt_gat);
  wconv_kernel<<<dim3(8, 32),  256, 0, stream>>>(in_proj_w, 256, 1024, bt_inp);
  wconv_kernel<<<dim3(16, 4),  256, 0, stream>>>(x_proj_w,  512, 17,   bt_xp);   // rows 17..127 zero
  wconv_kernel<<<dim3(16, 8),  256, 0, stream>>>(out_w,     512, 256,  bt_out);
  wconv_kernel<<<dim3(16, 8),  256, 0, stream>>>(mlp_w1,    512, 256,  bt_m1);
  wconv_kernel<<<dim3(8, 8),   256, 0, stream>>>(mlp_w2,    256, 256,  bt_m2);

  // 1. xcat_bf = permute(x) (bf16)
  permute_kernel<<<(3 * N_ * 64) / 256, 256, 0, stream>>>(x, xcat_bf);
  // 2. hop GEMM (fp32 out -> mlp1f) ; LN+silu -> xf_bf
  mgemm_kernel<<<dim3(256, 4), 256, 0, stream>>>(xcat_bf, 768, bt_hop, 768, 256, mlp1f, 256, 0, 0, hop_b, nullptr, 768);
  ln_silu_kernel<<<N_, 256, 0, stream>>>(mlp1f, xf_bf, hop_ln_g, hop_ln_b);
  // 3. h_bf = xf_bf @ gat_w (bf16 out)
  mgemm_kernel<<<dim3(256, 4), 256, 0, stream>>>(xf_bf, 256, bt_gat, 256, 256, h_bf, 256, 0, 1, nullptr, nullptr, 256);
  // 4. attention logits
  att_scores_kernel<<<N_ / 4, 256, 0, stream>>>(h_bf, att_src, att_dst, as_, ad_);
  // 5. CSR by dst + out-degree
  count_kernel<<<(ET_ + 255) / 256, 256, 0, stream>>>(ei, cnt, degO);
  scan_offsets_kernel<<<1, 1024, 0, stream>>>(cnt, off, cursor);
  scatter_kernel<<<(ET_ + 255) / 256, 256, 0, stream>>>(ei, cursor, csr);
  // 6. GAT -> cat_bf[:, :256] (wave-per-dst)
  gat_agg_kernel<<<N_ / 4, 256, 0, stream>>>(ei, off, csr, as_, ad_, h_bf, gat_b, cat_bf);
  // 7. stable argsort
  key_kernel<<<N_ / 256, 256, 0, stream>>>(degO, pnoise, keys);
  rank_part_kernel<<<dim3(N_ / 256, 32), 256, 0, stream>>>(keys, rank);
  rank_scatter_kernel<<<N_ / 256, 256, 0, stream>>>(rank, sidx);
  // 8. u0_bf = xf_bf[sidx]; xz_bf = u0_bf @ in_proj_w (bf16)
  gather_kernel<<<N_, 64, 0, stream>>>(xf_bf, sidx, u0_bf);
  mgemm_kernel<<<dim3(256, 16), 256, 0, stream>>>(u0_bf, 256, bt_inp, 256, 1024, xz_bf, 1024, 0, 1, nullptr, nullptr, 256);
  // 9. conv + silu -> xm_bf
  conv_silu_kernel<<<(N_ * 64) / 256, 256, 0, stream>>>(xz_bf, conv_w, xm_bf);
  // 10. x_dbl = xm_bf @ x_proj_w (N=17, fp32)
  mgemm_kernel<<<dim3(256, 1), 256, 0, stream>>>(xm_bf, 512, bt_xp, 512, 17, xdbl, 17, 0, 0, nullptr, nullptr, 512);
  // 11-13. selective scan -> y_bf
  scan_p1_kernel<<<dim3(2, CH_), 256, 0, stream>>>(xdbl, dt_w, dt_b, A_log, a_sum, b_final);
  scan_mid1_kernel<<<(NG_ * 16 * 512) / 256, 256, 0, stream>>>(a_sum, b_final, A_log, ga, gb);
  scan_mid2_kernel<<<32, 256, 0, stream>>>(ga, gb, A_log, ginit);
  scan_mid3_kernel<<<(NG_ * 16 * 512) / 256, 256, 0, stream>>>(a_sum, b_final, A_log, ginit, init);
  scan_p3_kernel<<<dim3(2, CH_), 256, 0, stream>>>(xdbl, dt_w, dt_b, A_log, init, xm_bf, D_param, xz_bf, y_bf);
  // 14. x_mamba = y_bf @ out_w + out_b -> cat_bf[:, 256:] (bf16, row-scattered)
  mgemm_kernel<<<dim3(256, 4), 256, 0, stream>>>(y_bf, 512, bt_out, 512, 256, cat_bf, 512, 256, 1, out_b, sidx, 512);
  // 15. MLP
  mgemm_kernel<<<dim3(256, 4), 256, 0, stream>>>(cat_bf, 512, bt_m1, 512, 256, mlp1f, 256, 0, 0, mlp_b1, nullptr, 512);
  ln_silu_kernel<<<N_, 256, 0, stream>>>(mlp1f, m1_bf, mlp_ln_g, mlp_ln_b);
  mgemm_kernel<<<dim3(256, 4), 256, 0, stream>>>(m1_bf, 256, bt_m2, 256, 256, out, 256, 0, 0, mlp_b2, nullptr, 256);
}